// Round 6
// baseline (285.161 us; speedup 1.0000x reference)
//
#include <hip/hip_runtime.h>

#define ZN 131072          // B*H*W rows
#define DD 64              // embedding dim
#define KK 1024            // codebook entries
#define BSTRIDE 262144     // 64*64*64 (per-batch stride in z)
#define DSTRIDE 4096       // per-d stride in z (H*W)
#define ZQ_ELEMS 8388608   // 32*64*64*64

// ---- workspace layout ----
// [0,8)                double   loss accumulator
// [8,12)               unsigned pair count
// [12,16)              unsigned overflow-row count
// [16,4112)            float    csq32[1024]    (numpy-emulated fp32)
// [4112,528400)        float    zsq32[131072]  (numpy-emulated fp32)
// [528400,1052688)     int      ovflist[131072]
// [1052688,2101264)    u64      pack[131072]   (ordered_dist<<32 | k)
// [2363408,2625552)    ushort   cbB[64][2][2][64][8]  bf16 hi/lo B-fragments
// [2625552, +8MB)      u32      pairs[] = (n<<10 | k) candidate list
#define WS_CSQ_OFF   16
#define WS_ZSQ_OFF   4112
#define WS_OVF_OFF   528400
#define WS_PACK_OFF  1052688
#define WS_CBB_OFF   2363408
#define WS_PAIR_OFF  2625552
#define PAIR_CAP     2097152u

#define RF_CAND 32

typedef __attribute__((ext_vector_type(8))) short short8;
typedef __attribute__((ext_vector_type(4))) float f32x4;

// round-to-nearest-even fp32 -> bf16 (data has no NaN/Inf)
__device__ __forceinline__ unsigned short f2bf_rne(float x) {
    unsigned u = __float_as_uint(x);
    return (unsigned short)((u + 0x7fffu + ((u >> 16) & 1u)) >> 16);
}

// numpy-emulated fp32 sum of a[i]^2 over 64 elems (pairwise, 8 accumulators).
__device__ __forceinline__ float np_sumsq64(const float* a) {
    float r0 = __fmul_rn(a[0], a[0]), r1 = __fmul_rn(a[1], a[1]);
    float r2 = __fmul_rn(a[2], a[2]), r3 = __fmul_rn(a[3], a[3]);
    float r4 = __fmul_rn(a[4], a[4]), r5 = __fmul_rn(a[5], a[5]);
    float r6 = __fmul_rn(a[6], a[6]), r7 = __fmul_rn(a[7], a[7]);
#pragma unroll
    for (int i = 8; i < 64; i += 8) {
        r0 = __fadd_rn(r0, __fmul_rn(a[i + 0], a[i + 0]));
        r1 = __fadd_rn(r1, __fmul_rn(a[i + 1], a[i + 1]));
        r2 = __fadd_rn(r2, __fmul_rn(a[i + 2], a[i + 2]));
        r3 = __fadd_rn(r3, __fmul_rn(a[i + 3], a[i + 3]));
        r4 = __fadd_rn(r4, __fmul_rn(a[i + 4], a[i + 4]));
        r5 = __fadd_rn(r5, __fmul_rn(a[i + 5], a[i + 5]));
        r6 = __fadd_rn(r6, __fmul_rn(a[i + 6], a[i + 6]));
        r7 = __fadd_rn(r7, __fmul_rn(a[i + 7], a[i + 7]));
    }
    return __fadd_rn(__fadd_rn(__fadd_rn(r0, r1), __fadd_rn(r2, r3)),
                     __fadd_rn(__fadd_rn(r4, r5), __fadd_rn(r6, r7)));
}

// Merged: csq (numpy fp32) + bf16 hi/lo B-fragment prep. One thread per code.
// B frag for v_mfma_f32_16x16x32_bf16: col = lane&15, k = (lane>>4)*8 + j.
__global__ __launch_bounds__(256) void vq_prep(const float* __restrict__ cb,
                                               float* __restrict__ csq,
                                               unsigned short* __restrict__ cbB) {
    int k = blockIdx.x * 256 + threadIdx.x;
    const float* cp = cb + k * DD;
    csq[k] = np_sumsq64(cp);
    int ct = k >> 4, col = k & 15;
#pragma unroll
    for (int d = 0; d < DD; ++d) {
        float c = cp[d];
        unsigned short hi = f2bf_rne(c);
        float hf = __uint_as_float((unsigned)hi << 16);
        unsigned short lo = f2bf_rne(c - hf);
        int s = d >> 5, lg = (d >> 3) & 3, j = d & 7;
        int lane = col + 16 * lg;
        int base = ct * 2048 + s * 512 + lane * 8 + j;
        cbB[base] = hi;          // h = 0
        cbB[base + 1024] = lo;   // h = 1
    }
}

// numpy-emulated fp32 ||z||^2 per row (needed by refine).
__global__ __launch_bounds__(256) void vq_zsq(const float* __restrict__ z,
                                              float* __restrict__ zsq32) {
    int n = blockIdx.x * 256 + threadIdx.x;
    int b = n >> 12, p = n & 4095;
    const float* zp = z + (size_t)b * BSTRIDE + p;
    float r[8];
#pragma unroll
    for (int j = 0; j < 8; ++j) {
        float v = zp[(size_t)j * DSTRIDE];
        r[j] = __fmul_rn(v, v);
    }
#pragma unroll
    for (int i = 8; i < 64; i += 8)
#pragma unroll
        for (int j = 0; j < 8; ++j) {
            float v = zp[(size_t)(i + j) * DSTRIDE];
            r[j] = __fadd_rn(r[j], __fmul_rn(v, v));
        }
    zsq32[n] = __fadd_rn(__fadd_rn(__fadd_rn(r[0], r[1]), __fadd_rn(r[2], r[3])),
                         __fadd_rn(__fadd_rn(r[4], r[5]), __fadd_rn(r[6], r[7])));
}

// dist computation: two independent 3-chains.
#define MFMA_DIST(P, Q, A_H0, A_H1, A_L0, A_L1, B0, B1, B2, B3)               \
    P = __builtin_amdgcn_mfma_f32_16x16x32_bf16(A_H0, B0, P, 0, 0, 0);        \
    Q = __builtin_amdgcn_mfma_f32_16x16x32_bf16(A_H0, B2, Q, 0, 0, 0);        \
    P = __builtin_amdgcn_mfma_f32_16x16x32_bf16(A_H1, B1, P, 0, 0, 0);        \
    Q = __builtin_amdgcn_mfma_f32_16x16x32_bf16(A_H1, B3, Q, 0, 0, 0);        \
    P = __builtin_amdgcn_mfma_f32_16x16x32_bf16(A_L0, B0, P, 0, 0, 0);        \
    Q = __builtin_amdgcn_mfma_f32_16x16x32_bf16(A_L1, B1, Q, 0, 0, 0);

// -------- MFMA bf16^3 candidate-emitting scan --------
// block = 64 rows = 4 waves; wave w owns rows [16w,16w+16), scans all 1024
// codes (r4 structure: inline B loads, phase-locked every 8 ct for L1 reuse).
// Emits every (row,k) with dist < thr[row]+2e-4 where thr = 16-lane-shared
// running row-min (seeded by a 4-ct pre-pass, refreshed per phase). thr >=
// final row-min at all times, so the emitted set is a strict superset of all
// codes that can win under reference fp32 rounding (MFMA dist err ~4e-6, ref
// rounding noise ~2e-5 -> >=5x margin). No flags, no second MFMA pass.
// Rows with >RF_CAND candidates (or pair-buffer cap hit) -> overflow list.
__global__ __launch_bounds__(256)
void vq_scan(const float* __restrict__ z,
             const unsigned short* __restrict__ cbB,
             const float* __restrict__ csq,
             unsigned* __restrict__ paircnt,
             unsigned* __restrict__ ovfcnt,
             unsigned* __restrict__ pairs,
             int* __restrict__ ovflist,
             unsigned paircap) {
    __shared__ __align__(16) unsigned short aFrag[4][2][2][64][8];  // [rt][s][h][lane][j]
    __shared__ float scsq[1024];
    __shared__ int candCnt[64];
    __shared__ unsigned short candK[64][RF_CAND];

    int t = threadIdx.x;
    int n0 = blockIdx.x * 64;
    int b = n0 >> 12, p0 = n0 & 4095;   // 64 | 4096 -> no batch crossing in block

    for (int i = t; i < 1024; i += 256) scsq[i] = csq[i];
    if (t < 64) candCnt[t] = 0;

    {   // stage z tile: thread t loads row r = t&63, d-groups g = 2*(t>>6)+{0,1}
        int r = t & 63, gb = t >> 6;
        const float* zp = z + (size_t)b * BSTRIDE + p0 + r;
#pragma unroll
        for (int gg = 0; gg < 2; ++gg) {
            int g = (gb << 1) | gg;  // d in [8g, 8g+8)
            short8 hi8, lo8;
#pragma unroll
            for (int i2 = 0; i2 < 8; ++i2) {
                float v = zp[(size_t)(8 * g + i2) * DSTRIDE];  // coalesced across lanes
                unsigned short h = f2bf_rne(v);
                float hf = __uint_as_float((unsigned)h << 16);
                hi8[i2] = (short)h;
                lo8[i2] = (short)f2bf_rne(v - hf);
            }
            int rt = r >> 4, s = g >> 2, lane = (r & 15) + 16 * (g & 3);
            *(short8*)&aFrag[rt][s][0][lane][0] = hi8;
            *(short8*)&aFrag[rt][s][1][lane][0] = lo8;
        }
    }
    __syncthreads();

    int l = t & 63;
    int colcode = l & 15;
    int w = __builtin_amdgcn_readfirstlane(t >> 6);  // wave id = row-tile

    short8 aH0 = *(const short8*)&aFrag[w][0][0][l][0];
    short8 aH1 = *(const short8*)&aFrag[w][1][0][l][0];
    short8 aL0 = *(const short8*)&aFrag[w][0][1][l][0];
    short8 aL1 = *(const short8*)&aFrag[w][1][1][l][0];

    float m1[4];
#pragma unroll
    for (int r = 0; r < 4; ++r) m1[r] = 3.4e38f;

    int rowb = (w << 4) + ((l >> 4) << 2);

    // ---- pre-pass (cts 0,16,32,48): seed m1 so thr is never inf ----
#pragma unroll
    for (int pc = 0; pc < 4; ++pc) {
        int ct = pc << 4;
        const unsigned short* bp = cbB + ct * 2048 + (l << 3);
        short8 b0 = *(const short8*)(bp);
        short8 b1 = *(const short8*)(bp + 512);
        short8 b2 = *(const short8*)(bp + 1024);
        short8 b3 = *(const short8*)(bp + 1536);
        float cs = scsq[(ct << 4) + colcode];
        f32x4 p = {0.f, 0.f, 0.f, 0.f}, q = {0.f, 0.f, 0.f, 0.f};
        MFMA_DIST(p, q, aH0, aH1, aL0, aL1, b0, b1, b2, b3)
#pragma unroll
        for (int r = 0; r < 4; ++r)
            m1[r] = fminf(m1[r], fmaf(-2.f, p[r] + q[r], cs));
    }

    float thr[4];
    for (int ph = 0; ph < 8; ++ph) {
        __syncthreads();  // phase-lock the 4 waves for L1 B-frag reuse
        // refresh shared row-min threshold (16-lane butterfly)
#pragma unroll
        for (int r = 0; r < 4; ++r) {
            float v = m1[r];
            v = fminf(v, __shfl_xor(v, 1, 64));
            v = fminf(v, __shfl_xor(v, 2, 64));
            v = fminf(v, __shfl_xor(v, 4, 64));
            v = fminf(v, __shfl_xor(v, 8, 64));
            thr[r] = v + 2e-4f;
        }
#pragma unroll 2
        for (int c8 = 0; c8 < 8; ++c8) {
            int ct = (ph << 3) | c8;
            const unsigned short* bp = cbB + ct * 2048 + (l << 3);
            short8 b0 = *(const short8*)(bp);
            short8 b1 = *(const short8*)(bp + 512);
            short8 b2 = *(const short8*)(bp + 1024);
            short8 b3 = *(const short8*)(bp + 1536);
            float cs = scsq[(ct << 4) + colcode];
            unsigned code = (unsigned)((ct << 4) + colcode);
            f32x4 p = {0.f, 0.f, 0.f, 0.f}, q = {0.f, 0.f, 0.f, 0.f};
            MFMA_DIST(p, q, aH0, aH1, aL0, aL1, b0, b1, b2, b3)
#pragma unroll
            for (int r = 0; r < 4; ++r) {
                float dist = fmaf(-2.f, p[r] + q[r], cs);
                m1[r] = fminf(m1[r], dist);
                if (dist < thr[r]) {  // rare (~5-10 per row over whole loop)
                    int row = rowb + r;
                    int pos = atomicAdd(&candCnt[row], 1);
                    if (pos < RF_CAND) candK[row][pos] = (unsigned short)code;
                }
            }
        }
    }
    __syncthreads();

    // ---- flush: block-compacted pair emission, 1 global atomic each ----
    if (t < 64) {
        int c = candCnt[t];
        bool ovf = (c > RF_CAND);
        int cc = ovf ? 0 : c;
        int run = cc;  // inclusive prefix over 64 lanes
#pragma unroll
        for (int off = 1; off < 64; off <<= 1) {
            int o = __shfl_up(run, off, 64);
            if (t >= off) run += o;
        }
        int total = __shfl(run, 63, 64);
        unsigned base = 0;
        if (t == 63 && total) base = atomicAdd(paircnt, (unsigned)total);
        base = __shfl(base, 63, 64);
        bool fits = (base <= paircap) && (base + (unsigned)total <= paircap);
        bool toOvf = ovf || !fits;
        unsigned long long mb = __ballot(toOvf);
        int otot = __popcll(mb);
        unsigned obase = 0;
        if (t == 0 && otot) obase = atomicAdd(ovfcnt, (unsigned)otot);
        obase = __shfl(obase, 0, 64);
        if (toOvf) {
            int opre = __popcll(mb & ((1ull << t) - 1ull));
            ovflist[obase + opre] = n0 + t;
        } else {
            unsigned st = base + (unsigned)(run - cc);
            unsigned nn = (unsigned)(n0 + t) << 10;
            for (int i = 0; i < c; ++i)
                pairs[st + i] = nn | candK[t][i];
        }
    }
}

// fp64 reference-fp32-emulated distance (bit-identical to the validated
// refine of earlier rounds) -> order-preserving packed u64 (ties -> lowest k).
__device__ __forceinline__ unsigned long long ref_pack(const float* zp,
                                                       const float* cp,
                                                       float zsqn, float csqk,
                                                       unsigned k) {
    double a0 = 0.0, a1 = 0.0, a2 = 0.0, a3 = 0.0;
#pragma unroll
    for (int d = 0; d < DD; d += 4) {
        a0 = fma((double)zp[(size_t)(d + 0) * DSTRIDE], (double)cp[d + 0], a0);
        a1 = fma((double)zp[(size_t)(d + 1) * DSTRIDE], (double)cp[d + 1], a1);
        a2 = fma((double)zp[(size_t)(d + 2) * DSTRIDE], (double)cp[d + 2], a2);
        a3 = fma((double)zp[(size_t)(d + 3) * DSTRIDE], (double)cp[d + 3], a3);
    }
    double dot = (a0 + a1) + (a2 + a3);
    float twoC = (float)(2.0 * dot);               // ~sgemm output, correctly rounded
    float dist = __fsub_rn(__fadd_rn(zsqn, csqk), twoC);  // reference fp32 ops
    unsigned ub = __float_as_uint(dist);
    ub = (ub & 0x80000000u) ? ~ub : (ub | 0x80000000u);   // order-preserving map
    return ((unsigned long long)ub << 32) | k;
}

// -------- exact refine over candidate pairs + overflow rows --------
// Extra/stale pairs are harmless: every pair is scored with the same exact
// reference metric, so atomicMin can only converge to the true argmin
// (ties -> lowest k, matching jnp.argmin). n is range-guarded.
__global__ __launch_bounds__(256) void vq_refine_pairs(
    const float* __restrict__ z,
    const float* __restrict__ cb,
    const float* __restrict__ csq,
    const float* __restrict__ zsq32,
    const unsigned* __restrict__ paircnt,
    const unsigned* __restrict__ ovfcnt,
    const unsigned* __restrict__ pairs,
    const int* __restrict__ ovflist,
    unsigned paircap,
    unsigned long long* __restrict__ pack) {
    unsigned stride = gridDim.x * 256;
    unsigned tid = blockIdx.x * 256 + threadIdx.x;

    unsigned cnt = *paircnt;
    if (cnt > paircap) cnt = paircap;
    for (unsigned i = tid; i < cnt; i += stride) {
        unsigned pr = pairs[i];
        unsigned n = pr >> 10;
        if (n < (unsigned)ZN) {
            unsigned k = pr & 1023u;
            int b = n >> 12, p = n & 4095;
            const float* zp = z + (size_t)b * BSTRIDE + p;
            unsigned long long pk =
                ref_pack(zp, cb + k * DD, zsq32[n], csq[k], k);
            atomicMin(&pack[n], pk);
        }
    }

    // overflow rows: full 1024-code exact scan
    unsigned long long tot2 = (unsigned long long)(*ovfcnt) << 10;
    for (unsigned long long wk = tid; wk < tot2; wk += stride) {
        unsigned r = (unsigned)(wk >> 10);
        unsigned k = (unsigned)(wk & 1023u);
        int n = ovflist[r];
        int b = n >> 12, p = n & 4095;
        const float* zp = z + (size_t)b * BSTRIDE + p;
        unsigned long long pk = ref_pack(zp, cb + k * DD, zsq32[n], csq[k], k);
        atomicMin(&pack[n], pk);
    }
}

// -------- gather z_q + idx writeback + loss partial reduction --------
__global__ __launch_bounds__(256) void vq_gather_loss(const float* __restrict__ z,
                                                      const float* __restrict__ cb,
                                                      const unsigned long long* __restrict__ pack,
                                                      float* __restrict__ idxf,
                                                      float* __restrict__ zq_out,
                                                      double* __restrict__ acc) {
    int n = blockIdx.x * 256 + threadIdx.x;
    int b = n >> 12, p = n & 4095;
    const float* zp = z + (size_t)b * BSTRIDE + p;
    float* qp = zq_out + (size_t)b * BSTRIDE + p;

    int k = (int)(unsigned)(pack[n] & 1023ull);  // every row has candidates
    idxf[n] = (float)k;
    const float* c = cb + k * DD;

    float s = 0.f;
#pragma unroll
    for (int d = 0; d < DD; ++d) {
        float q = c[d];
        float diff = q - zp[(size_t)d * DSTRIDE];
        s = fmaf(diff, diff, s);
        qp[(size_t)d * DSTRIDE] = q;  // z_q_st == z_q numerically
    }

#pragma unroll
    for (int off = 32; off; off >>= 1) s += __shfl_down(s, off, 64);
    __shared__ float partial[4];
    if ((threadIdx.x & 63) == 0) partial[threadIdx.x >> 6] = s;
    __syncthreads();
    if (threadIdx.x == 0) {
        float t = (partial[0] + partial[1]) + (partial[2] + partial[3]);
        atomicAdd(acc, (double)t);
    }
}

__global__ void vq_finalize(const double* __restrict__ acc, float* __restrict__ loss_out) {
    *loss_out = (float)(1.25 * (*acc) / (double)ZQ_ELEMS);
}

extern "C" void kernel_launch(void* const* d_in, const int* in_sizes, int n_in,
                              void* d_out, int out_size, void* d_ws, size_t ws_size,
                              hipStream_t stream) {
    const float* z = (const float*)d_in[0];
    const float* cb = (const float*)d_in[1];
    float* out = (float*)d_out;

    float* zq_out = out;                   // [0, 8388608)
    float* loss_out = out + ZQ_ELEMS;      // [8388608]
    float* idxf_out = out + ZQ_ELEMS + 1;  // [8388609, +131072)

    char* ws = (char*)d_ws;
    double* acc = (double*)ws;
    unsigned* paircnt = (unsigned*)(ws + 8);
    unsigned* ovfcnt = (unsigned*)(ws + 12);
    float* csq = (float*)(ws + WS_CSQ_OFF);
    float* zsq32 = (float*)(ws + WS_ZSQ_OFF);
    int* ovflist = (int*)(ws + WS_OVF_OFF);
    unsigned long long* pack = (unsigned long long*)(ws + WS_PACK_OFF);
    unsigned short* cbB = (unsigned short*)(ws + WS_CBB_OFF);
    unsigned* pairs = (unsigned*)(ws + WS_PAIR_OFF);

    unsigned paircap = 0;
    if (ws_size > WS_PAIR_OFF)
        paircap = (unsigned)((ws_size - WS_PAIR_OFF) / 4);
    if (paircap > PAIR_CAP) paircap = PAIR_CAP;

    hipMemsetAsync(d_ws, 0, 16, stream);                     // acc, paircnt, ovfcnt
    hipMemsetAsync(ws + WS_PACK_OFF, 0xFF, ZN * 8, stream);  // pack = UINT64_MAX

    vq_prep<<<KK / 256, 256, 0, stream>>>(cb, csq, cbB);
    vq_zsq<<<ZN / 256, 256, 0, stream>>>(z, zsq32);
    vq_scan<<<ZN / 64, 256, 0, stream>>>(z, cbB, csq, paircnt, ovfcnt,
                                         pairs, ovflist, paircap);
    vq_refine_pairs<<<1024, 256, 0, stream>>>(z, cb, csq, zsq32, paircnt, ovfcnt,
                                              pairs, ovflist, paircap, pack);
    vq_gather_loss<<<ZN / 256, 256, 0, stream>>>(z, cb, pack, idxf_out, zq_out, acc);
    vq_finalize<<<1, 1, 0, stream>>>(acc, loss_out);
}